// Round 16
// baseline (241.457 us; speedup 1.0000x reference)
//
#include <hip/hip_runtime.h>

typedef __attribute__((ext_vector_type(8))) short short8;
typedef __attribute__((ext_vector_type(4))) float floatx4;

#define N_    2
#define LQ_   21760
#define D_    256
#define M_    8
#define L_    4
#define P_    4
#define DH_   32
#define LEN_  21760
#define BQ    16

__constant__ int c_start[4] = {0, 16384, 20480, 21504};
__constant__ int c_HW[4]    = {128, 64, 32, 16};

// ws layout (bytes):
//   vproj bf16 [N*M][LEN_][32] @ 0  (22,282,240 B)
//   wt bf16: Wofft[256][256] @ elem 0, Wattt[128][256] @ 65536,
//            Woutt[256][256] @ 98304, Wvt[256][256] @ 163840
#define WT_BYTE_OFF 22282240u

__device__ __forceinline__ unsigned short f2bf(float f) {
  unsigned int u = __builtin_bit_cast(unsigned int, f);
  u += 0x7fffu + ((u >> 16) & 1u);   // RNE
  return (unsigned short)(u >> 16);
}
__device__ __forceinline__ float bf2f(unsigned short s) {
  return __builtin_bit_cast(float, ((unsigned int)s) << 16);
}
__device__ __forceinline__ float bflo(unsigned int u) {
  return __builtin_bit_cast(float, u << 16);
}
__device__ __forceinline__ float bfhi(unsigned int u) {
  return __builtin_bit_cast(float, u & 0xffff0000u);
}

__device__ __forceinline__ void fma8v(const uint4 u, const float w,
    float& a0, float& a1, float& a2, float& a3,
    float& a4, float& a5, float& a6, float& a7) {
  a0 += bflo(u.x) * w; a1 += bfhi(u.x) * w;
  a2 += bflo(u.y) * w; a3 += bfhi(u.y) * w;
  a4 += bflo(u.z) * w; a5 += bfhi(u.z) * w;
  a6 += bflo(u.w) * w; a7 += bfhi(u.w) * w;
}

// ---------------- prep: transpose + convert weights to bf16 ----------------
__global__ __launch_bounds__(256) void prep_kernel(
    const float* __restrict__ Woff, const float* __restrict__ Watt,
    const float* __restrict__ Wout, const float* __restrict__ Wv,
    unsigned short* __restrict__ wt) {
  const int b = blockIdx.x, t = threadIdx.x;
  const float* src; int ncols, n; unsigned short* dst;
  if (b < 256)      { src = Woff; ncols = 256; n = b;       dst = wt + 0      + n * 256; }
  else if (b < 384) { src = Watt; ncols = 128; n = b - 256; dst = wt + 65536  + n * 256; }
  else if (b < 640) { src = Wout; ncols = 256; n = b - 384; dst = wt + 98304  + n * 256; }
  else              { src = Wv;   ncols = 256; n = b - 640; dst = wt + 163840 + n * 256; }
  dst[t] = f2bf(src[(size_t)t * ncols + n]);
}

// ---------------- vproj: value @ W_val + b_val -> bf16 [n][m][pix][32] -----
__global__ __launch_bounds__(256, 2) void vproj_kernel(
    const float* __restrict__ value, const unsigned short* __restrict__ Wvt,
    const float* __restrict__ bv, unsigned short* __restrict__ vout) {
  __shared__ unsigned short vs[64][264];
  const int t = threadIdx.x;
  const int r0 = blockIdx.x * 64;
  {
    const int c2 = (t & 127) * 2;
    const int rb = t >> 7;
#pragma unroll
    for (int i = 0; i < 32; ++i) {
      int rr = rb + i * 2;
      float2 v = *(const float2*)(value + (size_t)(r0 + rr) * D_ + c2);
      *(unsigned int*)&vs[rr][c2] = (unsigned int)f2bf(v.x) | ((unsigned int)f2bf(v.y) << 16);
    }
  }
  __syncthreads();
  const int wave = t >> 6, lane = t & 63;
  const int arow = wave * 16 + (lane & 15);
  const int kg = (lane >> 4) * 8;
  floatx4 acc[16] = {};
  for (int kk = 0; kk < 8; ++kk) {
    const int k0 = kk * 32;
    short8 af = *(const short8*)&vs[arow][k0 + kg];
#pragma unroll
    for (int ct = 0; ct < 16; ++ct) {
      const int col = ct * 16 + (lane & 15);
      short8 bf = *(const short8*)(Wvt + col * 256 + k0 + kg);
      acc[ct] = __builtin_amdgcn_mfma_f32_16x16x32_bf16(af, bf, acc[ct], 0, 0, 0);
    }
  }
  const int n = (r0 >= LEN_) ? 1 : 0;
  const int pixbase = r0 - n * LEN_ + wave * 16 + ((lane >> 4) * 4);
#pragma unroll
  for (int ct = 0; ct < 16; ++ct) {
    const int gc = ct * 16 + (lane & 15);
    const int m = gc >> 5, d = gc & 31;
    const float bb = bv[gc];
    unsigned short* ob = vout + ((size_t)(n * M_ + m) * LEN_) * DH_ + d;
#pragma unroll
    for (int j = 0; j < 4; ++j)
      ob[(size_t)(pixbase + j) * DH_] = f2bf(acc[ct][j] + bb);
  }
}

// ---------------- msda: fused proj/softmax/sample/out ----------------------
__global__ __launch_bounds__(256, 4)
void msda_kernel(
    const float* __restrict__ query, const float* __restrict__ refp,
    const unsigned short* __restrict__ wt,
    const float* __restrict__ boff, const float* __restrict__ batt,
    const float* __restrict__ bout,
    const unsigned short* __restrict__ vproj, float* __restrict__ out) {
  __shared__ unsigned short qs[BQ][264];    // Q (bf16); reused as mid (bf16)
  __shared__ unsigned short offb[BQ][256];  // offsets, bf16
  __shared__ float awb[BQ][128];            // attn logits -> weights, f32
  __shared__ short sidx[4][2][2][16];       // [wave][qpar][head][sample]
  __shared__ float swls[4][2][2][16][4];    // [wave][qpar][head][sample][corner]

  const int t = threadIdx.x;
  // XCD-chunked swizzle: 2720 blocks = 8 XCDs x 340; each XCD serves one n.
  const int lb = (blockIdx.x & 7) * 340 + (blockIdx.x >> 3);
  const int qg0 = lb * BQ;
  const int n = qg0 / LQ_;

  {  // stage Q -> bf16 LDS
    const int c2 = (t & 127) * 2;
    const int rb = t >> 7;
#pragma unroll
    for (int i = 0; i < 8; ++i) {
      int rr = rb + i * 2;
      float2 v = *(const float2*)(query + (size_t)(qg0 + rr) * D_ + c2);
      *(unsigned int*)&qs[rr][c2] = (unsigned int)f2bf(v.x) | ((unsigned int)f2bf(v.y) << 16);
    }
  }
  __syncthreads();

  const int wave = t >> 6, lane = t & 63;
  const int arow = lane & 15;
  const int kg = (lane >> 4) * 8;
  const int row0 = (lane >> 4) * 4;

  {  // off+att GEMM: [16x256] @ [256x384], wave covers 6 col-tiles
    floatx4 acc[6] = {};
    for (int kk = 0; kk < 8; ++kk) {
      const int k0 = kk * 32;
      short8 af = *(const short8*)&qs[arow][k0 + kg];
#pragma unroll
      for (int i = 0; i < 6; ++i) {
        const int col = wave * 96 + i * 16 + (lane & 15);
        const unsigned short* bp = (col < 256) ? (wt + col * 256)
                                               : (wt + 65536 + (col - 256) * 256);
        short8 bf = *(const short8*)(bp + k0 + kg);
        acc[i] = __builtin_amdgcn_mfma_f32_16x16x32_bf16(af, bf, acc[i], 0, 0, 0);
      }
    }
#pragma unroll
    for (int i = 0; i < 6; ++i) {
      const int col = wave * 96 + i * 16 + (lane & 15);
      if (col < 256) {
        const float bb = boff[col];
#pragma unroll
        for (int j = 0; j < 4; ++j) offb[row0 + j][col] = f2bf(acc[i][j] + bb);
      } else {
        const float bb = batt[col - 256];
#pragma unroll
        for (int j = 0; j < 4; ++j) awb[row0 + j][col - 256] = acc[i][j] + bb;
      }
    }
  }
  __syncthreads();

  if (t < 128) {  // softmax over 16 per (q, m): q = t>>3, m = t&7
    const int q = t >> 3, m = t & 7;
    float v[16]; float mx = -1e30f;
#pragma unroll
    for (int s = 0; s < 16; ++s) { v[s] = awb[q][m * 16 + s]; mx = fmaxf(mx, v[s]); }
    float sum = 0.f;
#pragma unroll
    for (int s = 0; s < 16; ++s) { v[s] = __expf(v[s] - mx); sum += v[s]; }
    const float inv = 1.f / sum;
#pragma unroll
    for (int s = 0; s < 16; ++s) awb[q][m * 16 + s] = v[s] * inv;
  }
  __syncthreads();

  // ---- sampling: wave-private, zero barriers, forced-batch + pipelined ----
  const int qo  = lane >> 5;          // query parity within pair (setup)
  const int sh  = (lane >> 4) & 1;    // head within wave (setup)
  const int ss  = lane & 15;          // sample (setup)
  const int slv = ss >> 2;            // level
  const int WlS = 128 >> slv;
  const int stS = c_start[slv];
  const int st_eq = (2 * wave + sh) * 16 + ss;  // offb/awb column
  // gather mapping
  const int hg = lane >> 5;
  const int m_g = 2 * wave + hg;
  const int g = lane & 31;
  const int sp = g >> 4, rsel = (g >> 3) & 1, csel = (g >> 2) & 1;
  const int wsel = (g >> 2) & 3, doct = g & 3;
  const char* vbyte = (const char*)vproj + (size_t)(n * M_ + m_g) * LEN_ * DH_ * 2;

  const float2* refp2 = (const float2*)refp;

#define SETUP(EP)                                                            \
  {                                                                          \
    const int q_ = 2 * (EP) + qo;                                            \
    const float2 rpv = refp2[(size_t)(qg0 + q_) * 4 + slv];                  \
    const float gx = rpv.x * (float)WlS + bf2f(offb[q_][2 * st_eq]) - 0.5f;  \
    const float gy = rpv.y * (float)WlS + bf2f(offb[q_][2 * st_eq + 1]) - 0.5f; \
    const float fx0 = floorf(gx), fy0 = floorf(gy);                          \
    const int x0 = (int)fx0, y0 = (int)fy0;                                  \
    const float wx1 = gx - fx0, wy1 = gy - fy0;                              \
    const float wx0 = 1.f - wx1, wy0 = 1.f - wy1;                            \
    const float a = awb[q_][st_eq];                                          \
    const bool vx0 = (x0 >= 0) && (x0 < WlS);                                \
    const bool vx1 = (x0 + 1 >= 0) && (x0 + 1 < WlS);                        \
    const bool vy0 = (y0 >= 0) && (y0 < WlS);                                \
    const bool vy1 = (y0 + 1 >= 0) && (y0 + 1 < WlS);                        \
    sidx[wave][qo][sh][ss] = (short)(stS + y0 * WlS + x0);                   \
    swls[wave][qo][sh][ss][0] = (vy0 && vx0) ? wy0 * wx0 * a : 0.f;          \
    swls[wave][qo][sh][ss][1] = (vy0 && vx1) ? wy0 * wx1 * a : 0.f;          \
    swls[wave][qo][sh][ss][2] = (vy1 && vx0) ? wy1 * wx0 * a : 0.f;          \
    swls[wave][qo][sh][ss][3] = (vy1 && vx1) ? wy1 * wx1 * a : 0.f;          \
  }

  SETUP(0)

  for (int e = 0; e < 8; ++e) {
    // -- phase 1: ALL params for both queries of pair e -> registers,
    //    then 16 back-to-back global loads --
    const short* ipA = &sidx[wave][0][hg][0];
    const short* ipB = &sidx[wave][1][hg][0];
    const float* wpA = &swls[wave][0][hg][0][wsel];
    const float* wpB = &swls[wave][1][hg][0][wsel];
    uint4 uA0, uA1, uA2, uA3, uA4, uA5, uA6, uA7;
    uint4 uB0, uB1, uB2, uB3, uB4, uB5, uB6, uB7;
    float wA0, wA1, wA2, wA3, wA4, wA5, wA6, wA7;
    float wB0, wB1, wB2, wB3, wB4, wB5, wB6, wB7;
#define GLD(P, i, WLC)                                                       \
    {                                                                        \
      const int s_ = 2 * (i) + sp;                                           \
      const int ix_ = (int)ip##P[s_];                                        \
      w##P##i = wp##P[s_ * 4];                                               \
      int ofs_ = (ix_ + rsel * (WLC) + csel) * 64 + doct * 16;               \
      ofs_ = (ofs_ > 0) ? ofs_ : 0;                                          \
      u##P##i = *(const uint4*)(vbyte + ofs_);                               \
    }
    GLD(A, 0, 128) GLD(A, 1, 128) GLD(A, 2, 64) GLD(A, 3, 64)
    GLD(A, 4, 32)  GLD(A, 5, 32)  GLD(A, 6, 16) GLD(A, 7, 16)
    GLD(B, 0, 128) GLD(B, 1, 128) GLD(B, 2, 64) GLD(B, 3, 64)
    GLD(B, 4, 32)  GLD(B, 5, 32)  GLD(B, 6, 16) GLD(B, 7, 16)
#undef GLD
    __builtin_amdgcn_sched_barrier(0);

    // -- phase 2: setup(e+1) runs while the 16 loads are in flight --
    if (e < 7) SETUP(e + 1)
    __builtin_amdgcn_sched_barrier(0);

    // -- phase 3: consume A then B --
#define CONSUME(P, QP)                                                       \
    {                                                                        \
      float acc0 = 0.f, acc1 = 0.f, acc2 = 0.f, acc3 = 0.f;                  \
      float acc4 = 0.f, acc5 = 0.f, acc6 = 0.f, acc7 = 0.f;                  \
      fma8v(u##P##0, w##P##0, acc0, acc1, acc2, acc3, acc4, acc5, acc6, acc7); \
      fma8v(u##P##1, w##P##1, acc0, acc1, acc2, acc3, acc4, acc5, acc6, acc7); \
      fma8v(u##P##2, w##P##2, acc0, acc1, acc2, acc3, acc4, acc5, acc6, acc7); \
      fma8v(u##P##3, w##P##3, acc0, acc1, acc2, acc3, acc4, acc5, acc6, acc7); \
      fma8v(u##P##4, w##P##4, acc0, acc1, acc2, acc3, acc4, acc5, acc6, acc7); \
      fma8v(u##P##5, w##P##5, acc0, acc1, acc2, acc3, acc4, acc5, acc6, acc7); \
      fma8v(u##P##6, w##P##6, acc0, acc1, acc2, acc3, acc4, acc5, acc6, acc7); \
      fma8v(u##P##7, w##P##7, acc0, acc1, acc2, acc3, acc4, acc5, acc6, acc7); \
      acc0 += __shfl_xor(acc0, 4);  acc1 += __shfl_xor(acc1, 4);             \
      acc2 += __shfl_xor(acc2, 4);  acc3 += __shfl_xor(acc3, 4);             \
      acc4 += __shfl_xor(acc4, 4);  acc5 += __shfl_xor(acc5, 4);             \
      acc6 += __shfl_xor(acc6, 4);  acc7 += __shfl_xor(acc7, 4);             \
      acc0 += __shfl_xor(acc0, 8);  acc1 += __shfl_xor(acc1, 8);             \
      acc2 += __shfl_xor(acc2, 8);  acc3 += __shfl_xor(acc3, 8);             \
      acc4 += __shfl_xor(acc4, 8);  acc5 += __shfl_xor(acc5, 8);             \
      acc6 += __shfl_xor(acc6, 8);  acc7 += __shfl_xor(acc7, 8);             \
      acc0 += __shfl_xor(acc0, 16); acc1 += __shfl_xor(acc1, 16);            \
      acc2 += __shfl_xor(acc2, 16); acc3 += __shfl_xor(acc3, 16);            \
      acc4 += __shfl_xor(acc4, 16); acc5 += __shfl_xor(acc5, 16);            \
      acc6 += __shfl_xor(acc6, 16); acc7 += __shfl_xor(acc7, 16);            \
      if (g < 4) {                                                           \
        uint4 st4;                                                           \
        st4.x = (unsigned int)f2bf(acc0) | ((unsigned int)f2bf(acc1) << 16); \
        st4.y = (unsigned int)f2bf(acc2) | ((unsigned int)f2bf(acc3) << 16); \
        st4.z = (unsigned int)f2bf(acc4) | ((unsigned int)f2bf(acc5) << 16); \
        st4.w = (unsigned int)f2bf(acc6) | ((unsigned int)f2bf(acc7) << 16); \
        *(uint4*)&qs[QP][m_g * 32 + doct * 8] = st4;                         \
      }                                                                      \
    }
    CONSUME(A, 2 * e)
    CONSUME(B, 2 * e + 1)
#undef CONSUME
  }
#undef SETUP
  __syncthreads();

  {  // out GEMM: mid [16x256] @ Wout [256x256], wave covers 4 col-tiles
    floatx4 acc[4] = {};
    for (int kk = 0; kk < 8; ++kk) {
      const int k0 = kk * 32;
      short8 af = *(const short8*)&qs[arow][k0 + kg];
#pragma unroll
      for (int i = 0; i < 4; ++i) {
        const int col = wave * 64 + i * 16 + (lane & 15);
        short8 bf = *(const short8*)(wt + 98304 + col * 256 + k0 + kg);
        acc[i] = __builtin_amdgcn_mfma_f32_16x16x32_bf16(af, bf, acc[i], 0, 0, 0);
      }
    }
#pragma unroll
    for (int i = 0; i < 4; ++i) {
      const int col = wave * 64 + i * 16 + (lane & 15);
      const float bb = bout[col];
#pragma unroll
      for (int j = 0; j < 4; ++j)
        out[(size_t)(qg0 + row0 + j) * D_ + col] = acc[i][j] + bb;
    }
  }
}

extern "C" void kernel_launch(void* const* d_in, const int* in_sizes, int n_in,
                              void* d_out, int out_size, void* d_ws, size_t ws_size,
                              hipStream_t stream) {
  const float* query = (const float*)d_in[0];
  const float* refp  = (const float*)d_in[1];
  const float* value = (const float*)d_in[2];
  const float* Wv    = (const float*)d_in[4];
  const float* bv    = (const float*)d_in[5];
  const float* Woff  = (const float*)d_in[6];
  const float* boff  = (const float*)d_in[7];
  const float* Watt  = (const float*)d_in[8];
  const float* batt  = (const float*)d_in[9];
  const float* Wout  = (const float*)d_in[10];
  const float* bout  = (const float*)d_in[11];
  float* out = (float*)d_out;

  unsigned short* vproj = (unsigned short*)d_ws;
  unsigned short* wt    = (unsigned short*)((char*)d_ws + WT_BYTE_OFF);
  const unsigned short* Wvt = wt + 163840;

  dim3 blk(256);
  hipLaunchKernelGGL(prep_kernel, dim3(896), blk, 0, stream, Woff, Watt, Wout, Wv, wt);
  hipLaunchKernelGGL(vproj_kernel, dim3((N_ * LEN_) / 64), blk, 0, stream, value, Wvt, bv, vproj);
  hipLaunchKernelGGL(msda_kernel, dim3((N_ * LQ_) / BQ), blk, 0, stream,
                     query, refp, wt, boff, batt, bout, vproj, out);
}

// Round 17
// 232.445 us; speedup vs baseline: 1.0388x; 1.0388x over previous
//
#include <hip/hip_runtime.h>

typedef __attribute__((ext_vector_type(8))) short short8;
typedef __attribute__((ext_vector_type(4))) float floatx4;

#define N_    2
#define LQ_   21760
#define D_    256
#define M_    8
#define L_    4
#define P_    4
#define DH_   32
#define LEN_  21760
#define BQ    16

__constant__ int c_start[4] = {0, 16384, 20480, 21504};
__constant__ int c_HW[4]    = {128, 64, 32, 16};

// ws layout (bytes):
//   vproj bf16 [N*M][LEN_][32] @ 0  (22,282,240 B)
//   wt bf16: Wofft[256][256] @ elem 0, Wattt[128][256] @ 65536,
//            Woutt[256][256] @ 98304, Wvt[256][256] @ 163840
#define WT_BYTE_OFF 22282240u

__device__ __forceinline__ unsigned short f2bf(float f) {
  unsigned int u = __builtin_bit_cast(unsigned int, f);
  u += 0x7fffu + ((u >> 16) & 1u);   // RNE
  return (unsigned short)(u >> 16);
}
__device__ __forceinline__ float bf2f(unsigned short s) {
  return __builtin_bit_cast(float, ((unsigned int)s) << 16);
}
__device__ __forceinline__ float bflo(unsigned int u) {
  return __builtin_bit_cast(float, u << 16);
}
__device__ __forceinline__ float bfhi(unsigned int u) {
  return __builtin_bit_cast(float, u & 0xffff0000u);
}

// ---------------- prep: transpose + convert weights to bf16 ----------------
__global__ __launch_bounds__(256) void prep_kernel(
    const float* __restrict__ Woff, const float* __restrict__ Watt,
    const float* __restrict__ Wout, const float* __restrict__ Wv,
    unsigned short* __restrict__ wt) {
  const int b = blockIdx.x, t = threadIdx.x;
  const float* src; int ncols, n; unsigned short* dst;
  if (b < 256)      { src = Woff; ncols = 256; n = b;       dst = wt + 0      + n * 256; }
  else if (b < 384) { src = Watt; ncols = 128; n = b - 256; dst = wt + 65536  + n * 256; }
  else if (b < 640) { src = Wout; ncols = 256; n = b - 384; dst = wt + 98304  + n * 256; }
  else              { src = Wv;   ncols = 256; n = b - 640; dst = wt + 163840 + n * 256; }
  dst[t] = f2bf(src[(size_t)t * ncols + n]);
}

// ---------------- vproj: value @ W_val + b_val -> bf16 [n][m][pix][32] -----
__global__ __launch_bounds__(256, 2) void vproj_kernel(
    const float* __restrict__ value, const unsigned short* __restrict__ Wvt,
    const float* __restrict__ bv, unsigned short* __restrict__ vout) {
  __shared__ unsigned short vs[64][264];
  const int t = threadIdx.x;
  const int r0 = blockIdx.x * 64;
  {
    const int c2 = (t & 127) * 2;
    const int rb = t >> 7;
#pragma unroll
    for (int i = 0; i < 32; ++i) {
      int rr = rb + i * 2;
      float2 v = *(const float2*)(value + (size_t)(r0 + rr) * D_ + c2);
      *(unsigned int*)&vs[rr][c2] = (unsigned int)f2bf(v.x) | ((unsigned int)f2bf(v.y) << 16);
    }
  }
  __syncthreads();
  const int wave = t >> 6, lane = t & 63;
  const int arow = wave * 16 + (lane & 15);
  const int kg = (lane >> 4) * 8;
  floatx4 acc[16] = {};
  for (int kk = 0; kk < 8; ++kk) {
    const int k0 = kk * 32;
    short8 af = *(const short8*)&vs[arow][k0 + kg];
#pragma unroll
    for (int ct = 0; ct < 16; ++ct) {
      const int col = ct * 16 + (lane & 15);
      short8 bf = *(const short8*)(Wvt + col * 256 + k0 + kg);
      acc[ct] = __builtin_amdgcn_mfma_f32_16x16x32_bf16(af, bf, acc[ct], 0, 0, 0);
    }
  }
  const int n = (r0 >= LEN_) ? 1 : 0;
  const int pixbase = r0 - n * LEN_ + wave * 16 + ((lane >> 4) * 4);
#pragma unroll
  for (int ct = 0; ct < 16; ++ct) {
    const int gc = ct * 16 + (lane & 15);
    const int m = gc >> 5, d = gc & 31;
    const float bb = bv[gc];
    unsigned short* ob = vout + ((size_t)(n * M_ + m) * LEN_) * DH_ + d;
#pragma unroll
    for (int j = 0; j < 4; ++j)
      ob[(size_t)(pixbase + j) * DH_] = f2bf(acc[ct][j] + bb);
  }
}

// ---------------- msda: fused proj/softmax/sample/out ----------------------
__global__ __launch_bounds__(256, 5)
__attribute__((amdgpu_waves_per_eu(4, 5)))
void msda_kernel(
    const float* __restrict__ query, const float* __restrict__ refp,
    const unsigned short* __restrict__ wt,
    const float* __restrict__ boff, const float* __restrict__ batt,
    const float* __restrict__ bout,
    const unsigned short* __restrict__ vproj, float* __restrict__ out) {
  __shared__ unsigned short qs[BQ][264];    // Q (bf16); reused as mid (bf16)
  __shared__ unsigned short offb[BQ][256];  // offsets, bf16
  __shared__ float awb[BQ][128];            // attn logits -> weights, f32
  __shared__ short sidx[4][2][2][16];       // wave-private: [wave][qpar][head][sample]
  __shared__ float swls[4][2][2][16][4];    // wave-private corner weights

  const int t = threadIdx.x;
  // XCD-chunked swizzle: 2720 blocks = 8 XCDs x 340; each XCD serves one n.
  const int lb = (blockIdx.x & 7) * 340 + (blockIdx.x >> 3);
  const int qg0 = lb * BQ;
  const int n = qg0 / LQ_;

  {  // stage Q -> bf16 LDS
    const int c2 = (t & 127) * 2;
    const int rb = t >> 7;
#pragma unroll
    for (int i = 0; i < 8; ++i) {
      int rr = rb + i * 2;
      float2 v = *(const float2*)(query + (size_t)(qg0 + rr) * D_ + c2);
      *(unsigned int*)&qs[rr][c2] = (unsigned int)f2bf(v.x) | ((unsigned int)f2bf(v.y) << 16);
    }
  }
  __syncthreads();

  const int wave = t >> 6, lane = t & 63;
  const int arow = lane & 15;
  const int kg = (lane >> 4) * 8;
  const int row0 = (lane >> 4) * 4;

  {  // off+att GEMM: [16x256] @ [256x384], wave covers 6 col-tiles
    floatx4 acc[6] = {};
    for (int kk = 0; kk < 8; ++kk) {
      const int k0 = kk * 32;
      short8 af = *(const short8*)&qs[arow][k0 + kg];
#pragma unroll
      for (int i = 0; i < 6; ++i) {
        const int col = wave * 96 + i * 16 + (lane & 15);
        const unsigned short* bp = (col < 256) ? (wt + col * 256)
                                               : (wt + 65536 + (col - 256) * 256);
        short8 bf = *(const short8*)(bp + k0 + kg);
        acc[i] = __builtin_amdgcn_mfma_f32_16x16x32_bf16(af, bf, acc[i], 0, 0, 0);
      }
    }
#pragma unroll
    for (int i = 0; i < 6; ++i) {
      const int col = wave * 96 + i * 16 + (lane & 15);
      if (col < 256) {
        const float bb = boff[col];
#pragma unroll
        for (int j = 0; j < 4; ++j) offb[row0 + j][col] = f2bf(acc[i][j] + bb);
      } else {
        const float bb = batt[col - 256];
#pragma unroll
        for (int j = 0; j < 4; ++j) awb[row0 + j][col - 256] = acc[i][j] + bb;
      }
    }
  }
  __syncthreads();

  if (t < 128) {  // softmax over 16 per (q, m): q = t>>3, m = t&7
    const int q = t >> 3, m = t & 7;
    float v[16]; float mx = -1e30f;
#pragma unroll
    for (int s = 0; s < 16; ++s) { v[s] = awb[q][m * 16 + s]; mx = fmaxf(mx, v[s]); }
    float sum = 0.f;
#pragma unroll
    for (int s = 0; s < 16; ++s) { v[s] = __expf(v[s] - mx); sum += v[s]; }
    const float inv = 1.f / sum;
#pragma unroll
    for (int s = 0; s < 16; ++s) awb[q][m * 16 + s] = v[s] * inv;
  }
  __syncthreads();

  // ---- sampling: wave-private, zero barriers ----
  const int qo  = lane >> 5;          // query parity within pair
  const int sh  = (lane >> 4) & 1;    // head within wave
  const int ss  = lane & 15;          // sample
  const int slv = ss >> 2;            // level (fixed per lane)
  const int WlS = 128 >> slv;
  const int stS = c_start[slv];
  const int st_eq = (2 * wave + sh) * 16 + ss;  // offb/awb column
  // gather mapping (R10 layout)
  const int hg = lane >> 5;
  const int m_g = 2 * wave + hg;
  const int g = lane & 31;
  const int sp = g >> 4, rsel = (g >> 3) & 1, csel = (g >> 2) & 1;
  const int wsel = (g >> 2) & 3, doct = g & 3;
  const char* vbyte = (const char*)vproj + (size_t)(n * M_ + m_g) * LEN_ * DH_ * 2;

  const float2* refp2 = (const float2*)refp;
  float2 rp[8];
#pragma unroll
  for (int e = 0; e < 8; ++e)
    rp[e] = refp2[(size_t)(qg0 + 2 * e + qo) * 4 + slv];

  for (int e = 0; e < 8; ++e) {
    {  // setup 2 queries (wave-private; in-order LDS, no barrier)
      const int q = 2 * e + qo;
      const float gx = rp[e].x * (float)WlS + bf2f(offb[q][2 * st_eq])     - 0.5f;
      const float gy = rp[e].y * (float)WlS + bf2f(offb[q][2 * st_eq + 1]) - 0.5f;
      const float fx0 = floorf(gx), fy0 = floorf(gy);
      const int x0 = (int)fx0, y0 = (int)fy0;
      const float wx1 = gx - fx0, wy1 = gy - fy0;
      const float wx0 = 1.f - wx1, wy0 = 1.f - wy1;
      const float a = awb[q][st_eq];
      const bool vx0 = (x0 >= 0) && (x0 < WlS);
      const bool vx1 = (x0 + 1 >= 0) && (x0 + 1 < WlS);
      const bool vy0 = (y0 >= 0) && (y0 < WlS);
      const bool vy1 = (y0 + 1 >= 0) && (y0 + 1 < WlS);
      sidx[wave][qo][sh][ss] = (short)(stS + y0 * WlS + x0);
      swls[wave][qo][sh][ss][0] = (vy0 && vx0) ? wy0 * wx0 * a : 0.f;
      swls[wave][qo][sh][ss][1] = (vy0 && vx1) ? wy0 * wx1 * a : 0.f;
      swls[wave][qo][sh][ss][2] = (vy1 && vx0) ? wy1 * wx0 * a : 0.f;
      swls[wave][qo][sh][ss][3] = (vy1 && vx1) ? wy1 * wx1 * a : 0.f;
    }

#pragma unroll
    for (int qo2 = 0; qo2 < 2; ++qo2) {
      const int qp = 2 * e + qo2;
      uint4 u0, u1, u2, u3, u4, u5, u6, u7;
      float w0, w1, w2, w3, w4, w5, w6, w7;
#define GLD(i, WLC)                                                        \
      {                                                                    \
        const int s_ = 2 * (i) + sp;                                       \
        const int ix_ = (int)sidx[wave][qo2][hg][s_];                      \
        w##i = swls[wave][qo2][hg][s_][wsel];                              \
        int ofs_ = (ix_ + rsel * (WLC) + csel) * 64 + doct * 16;           \
        ofs_ = (ofs_ > 0) ? ofs_ : 0;                                      \
        u##i = *(const uint4*)(vbyte + ofs_);                              \
      }
      GLD(0, 128) GLD(1, 128) GLD(2, 64) GLD(3, 64)
      GLD(4, 32)  GLD(5, 32)  GLD(6, 16) GLD(7, 16)
#undef GLD

      __builtin_amdgcn_s_setprio(1);
      float acc0 = 0.f, acc1 = 0.f, acc2 = 0.f, acc3 = 0.f;
      float acc4 = 0.f, acc5 = 0.f, acc6 = 0.f, acc7 = 0.f;
#define FMA8(i)                                                            \
      acc0 += bflo(u##i.x) * w##i; acc1 += bfhi(u##i.x) * w##i;            \
      acc2 += bflo(u##i.y) * w##i; acc3 += bfhi(u##i.y) * w##i;            \
      acc4 += bflo(u##i.z) * w##i; acc5 += bfhi(u##i.z) * w##i;            \
      acc6 += bflo(u##i.w) * w##i; acc7 += bfhi(u##i.w) * w##i;
      FMA8(0) FMA8(1) FMA8(2) FMA8(3) FMA8(4) FMA8(5) FMA8(6) FMA8(7)
#undef FMA8

      acc0 += __shfl_xor(acc0, 4);  acc1 += __shfl_xor(acc1, 4);
      acc2 += __shfl_xor(acc2, 4);  acc3 += __shfl_xor(acc3, 4);
      acc4 += __shfl_xor(acc4, 4);  acc5 += __shfl_xor(acc5, 4);
      acc6 += __shfl_xor(acc6, 4);  acc7 += __shfl_xor(acc7, 4);
      acc0 += __shfl_xor(acc0, 8);  acc1 += __shfl_xor(acc1, 8);
      acc2 += __shfl_xor(acc2, 8);  acc3 += __shfl_xor(acc3, 8);
      acc4 += __shfl_xor(acc4, 8);  acc5 += __shfl_xor(acc5, 8);
      acc6 += __shfl_xor(acc6, 8);  acc7 += __shfl_xor(acc7, 8);
      acc0 += __shfl_xor(acc0, 16); acc1 += __shfl_xor(acc1, 16);
      acc2 += __shfl_xor(acc2, 16); acc3 += __shfl_xor(acc3, 16);
      acc4 += __shfl_xor(acc4, 16); acc5 += __shfl_xor(acc5, 16);
      acc6 += __shfl_xor(acc6, 16); acc7 += __shfl_xor(acc7, 16);

      if (g < 4) {
        uint4 st4;
        st4.x = (unsigned int)f2bf(acc0) | ((unsigned int)f2bf(acc1) << 16);
        st4.y = (unsigned int)f2bf(acc2) | ((unsigned int)f2bf(acc3) << 16);
        st4.z = (unsigned int)f2bf(acc4) | ((unsigned int)f2bf(acc5) << 16);
        st4.w = (unsigned int)f2bf(acc6) | ((unsigned int)f2bf(acc7) << 16);
        *(uint4*)&qs[qp][m_g * 32 + doct * 8] = st4;
      }
      __builtin_amdgcn_s_setprio(0);
    }
  }
  __syncthreads();

  {  // out GEMM: mid [16x256] @ Wout [256x256], wave covers 4 col-tiles
    floatx4 acc[4] = {};
    for (int kk = 0; kk < 8; ++kk) {
      const int k0 = kk * 32;
      short8 af = *(const short8*)&qs[arow][k0 + kg];
#pragma unroll
      for (int i = 0; i < 4; ++i) {
        const int col = wave * 64 + i * 16 + (lane & 15);
        short8 bf = *(const short8*)(wt + 98304 + col * 256 + k0 + kg);
        acc[i] = __builtin_amdgcn_mfma_f32_16x16x32_bf16(af, bf, acc[i], 0, 0, 0);
      }
    }
#pragma unroll
    for (int i = 0; i < 4; ++i) {
      const int col = wave * 64 + i * 16 + (lane & 15);
      const float bb = bout[col];
#pragma unroll
      for (int j = 0; j < 4; ++j)
        out[(size_t)(qg0 + row0 + j) * D_ + col] = acc[i][j] + bb;
    }
  }
}

extern "C" void kernel_launch(void* const* d_in, const int* in_sizes, int n_in,
                              void* d_out, int out_size, void* d_ws, size_t ws_size,
                              hipStream_t stream) {
  const float* query = (const float*)d_in[0];
  const float* refp  = (const float*)d_in[1];
  const float* value = (const float*)d_in[2];
  const float* Wv    = (const float*)d_in[4];
  const float* bv    = (const float*)d_in[5];
  const float* Woff  = (const float*)d_in[6];
  const float* boff  = (const float*)d_in[7];
  const float* Watt  = (const float*)d_in[8];
  const float* batt  = (const float*)d_in[9];
  const float* Wout  = (const float*)d_in[10];
  const float* bout  = (const float*)d_in[11];
  float* out = (float*)d_out;

  unsigned short* vproj = (unsigned short*)d_ws;
  unsigned short* wt    = (unsigned short*)((char*)d_ws + WT_BYTE_OFF);
  const unsigned short* Wvt = wt + 163840;

  dim3 blk(256);
  hipLaunchKernelGGL(prep_kernel, dim3(896), blk, 0, stream, Woff, Watt, Wout, Wv, wt);
  hipLaunchKernelGGL(vproj_kernel, dim3((N_ * LEN_) / 64), blk, 0, stream, value, Wvt, bv, vproj);
  hipLaunchKernelGGL(msda_kernel, dim3((N_ * LQ_) / BQ), blk, 0, stream,
                     query, refp, wt, boff, batt, bout, vproj, out);
}

// Round 19
// 232.281 us; speedup vs baseline: 1.0395x; 1.0007x over previous
//
#include <hip/hip_runtime.h>

typedef __attribute__((ext_vector_type(8))) short short8;
typedef __attribute__((ext_vector_type(4))) float floatx4;

#define N_    2
#define LQ_   21760
#define D_    256
#define M_    8
#define L_    4
#define P_    4
#define DH_   32
#define LEN_  21760
#define BQ    16

__constant__ int c_start[4] = {0, 16384, 20480, 21504};
__constant__ int c_HW[4]    = {128, 64, 32, 16};

// ws layout (bytes):
//   vproj bf16 [N*M][LEN_][32] @ 0  (22,282,240 B)
//   wt bf16: Wofft[256][256] @ elem 0, Wattt[128][256] @ 65536,
//            Woutt[256][256] @ 98304, Wvt[256][256] @ 163840
#define WT_BYTE_OFF 22282240u

__device__ __forceinline__ unsigned short f2bf(float f) {
  unsigned int u = __builtin_bit_cast(unsigned int, f);
  u += 0x7fffu + ((u >> 16) & 1u);   // RNE
  return (unsigned short)(u >> 16);
}
__device__ __forceinline__ float bf2f(unsigned short s) {
  return __builtin_bit_cast(float, ((unsigned int)s) << 16);
}
__device__ __forceinline__ float bflo(unsigned int u) {
  return __builtin_bit_cast(float, u << 16);
}
__device__ __forceinline__ float bfhi(unsigned int u) {
  return __builtin_bit_cast(float, u & 0xffff0000u);
}

// ---------------- prep: transpose + convert weights to bf16 ----------------
__global__ __launch_bounds__(256) void prep_kernel(
    const float* __restrict__ Woff, const float* __restrict__ Watt,
    const float* __restrict__ Wout, const float* __restrict__ Wv,
    unsigned short* __restrict__ wt) {
  const int b = blockIdx.x, t = threadIdx.x;
  const float* src; int ncols, n; unsigned short* dst;
  if (b < 256)      { src = Woff; ncols = 256; n = b;       dst = wt + 0      + n * 256; }
  else if (b < 384) { src = Watt; ncols = 128; n = b - 256; dst = wt + 65536  + n * 256; }
  else if (b < 640) { src = Wout; ncols = 256; n = b - 384; dst = wt + 98304  + n * 256; }
  else              { src = Wv;   ncols = 256; n = b - 640; dst = wt + 163840 + n * 256; }
  dst[t] = f2bf(src[(size_t)t * ncols + n]);
}

// ---------------- vproj: value @ W_val + b_val -> bf16 [n][m][pix][32] -----
__global__ __launch_bounds__(256, 2) void vproj_kernel(
    const float* __restrict__ value, const unsigned short* __restrict__ Wvt,
    const float* __restrict__ bv, unsigned short* __restrict__ vout) {
  __shared__ unsigned short vs[64][264];
  const int t = threadIdx.x;
  const int r0 = blockIdx.x * 64;
  {
    const int c2 = (t & 127) * 2;
    const int rb = t >> 7;
#pragma unroll
    for (int i = 0; i < 32; ++i) {
      int rr = rb + i * 2;
      float2 v = *(const float2*)(value + (size_t)(r0 + rr) * D_ + c2);
      *(unsigned int*)&vs[rr][c2] = (unsigned int)f2bf(v.x) | ((unsigned int)f2bf(v.y) << 16);
    }
  }
  __syncthreads();
  const int wave = t >> 6, lane = t & 63;
  const int arow = wave * 16 + (lane & 15);
  const int kg = (lane >> 4) * 8;
  floatx4 acc[16] = {};
  for (int kk = 0; kk < 8; ++kk) {
    const int k0 = kk * 32;
    short8 af = *(const short8*)&vs[arow][k0 + kg];
#pragma unroll
    for (int ct = 0; ct < 16; ++ct) {
      const int col = ct * 16 + (lane & 15);
      short8 bf = *(const short8*)(Wvt + col * 256 + k0 + kg);
      acc[ct] = __builtin_amdgcn_mfma_f32_16x16x32_bf16(af, bf, acc[ct], 0, 0, 0);
    }
  }
  const int n = (r0 >= LEN_) ? 1 : 0;
  const int pixbase = r0 - n * LEN_ + wave * 16 + ((lane >> 4) * 4);
#pragma unroll
  for (int ct = 0; ct < 16; ++ct) {
    const int gc = ct * 16 + (lane & 15);
    const int m = gc >> 5, d = gc & 31;
    const float bb = bv[gc];
    unsigned short* ob = vout + ((size_t)(n * M_ + m) * LEN_) * DH_ + d;
#pragma unroll
    for (int j = 0; j < 4; ++j)
      ob[(size_t)(pixbase + j) * DH_] = f2bf(acc[ct][j] + bb);
  }
}

// ---------------- msda: fused proj/softmax/sample/out ----------------------
__global__ __launch_bounds__(256, 5)
__attribute__((amdgpu_waves_per_eu(4, 5)))
void msda_kernel(
    const float* __restrict__ query, const float* __restrict__ refp,
    const unsigned short* __restrict__ wt,
    const float* __restrict__ boff, const float* __restrict__ batt,
    const float* __restrict__ bout,
    const unsigned short* __restrict__ vproj, float* __restrict__ out) {
  __shared__ unsigned short qs[BQ][264];    // Q (bf16); reused as mid (bf16)
  __shared__ unsigned short offb[BQ][256];  // offsets, bf16
  __shared__ float awb[BQ][128];            // attn logits -> weights, f32
  __shared__ short sidx[4][2][2][16];       // wave-private: [wave][qpar][head][sample]
  __shared__ float swls[4][2][2][16][4];    // wave-private corner weights

  const int t = threadIdx.x;
  // XCD-chunked swizzle: 2720 blocks = 8 XCDs x 340; each XCD serves one n.
  const int lb = (blockIdx.x & 7) * 340 + (blockIdx.x >> 3);
  const int qg0 = lb * BQ;
  const int n = qg0 / LQ_;

  {  // stage Q -> bf16 LDS
    const int c2 = (t & 127) * 2;
    const int rb = t >> 7;
#pragma unroll
    for (int i = 0; i < 8; ++i) {
      int rr = rb + i * 2;
      float2 v = *(const float2*)(query + (size_t)(qg0 + rr) * D_ + c2);
      *(unsigned int*)&qs[rr][c2] = (unsigned int)f2bf(v.x) | ((unsigned int)f2bf(v.y) << 16);
    }
  }
  __syncthreads();

  const int wave = t >> 6, lane = t & 63;
  const int arow = lane & 15;
  const int kg = (lane >> 4) * 8;
  const int row0 = (lane >> 4) * 4;

  {  // off+att GEMM: [16x256] @ [256x384], wave covers 6 col-tiles
    floatx4 acc[6] = {};
    for (int kk = 0; kk < 8; ++kk) {
      const int k0 = kk * 32;
      short8 af = *(const short8*)&qs[arow][k0 + kg];
#pragma unroll
      for (int i = 0; i < 6; ++i) {
        const int col = wave * 96 + i * 16 + (lane & 15);
        const unsigned short* bp = (col < 256) ? (wt + col * 256)
                                               : (wt + 65536 + (col - 256) * 256);
        short8 bf = *(const short8*)(bp + k0 + kg);
        acc[i] = __builtin_amdgcn_mfma_f32_16x16x32_bf16(af, bf, acc[i], 0, 0, 0);
      }
    }
#pragma unroll
    for (int i = 0; i < 6; ++i) {
      const int col = wave * 96 + i * 16 + (lane & 15);
      if (col < 256) {
        const float bb = boff[col];
#pragma unroll
        for (int j = 0; j < 4; ++j) offb[row0 + j][col] = f2bf(acc[i][j] + bb);
      } else {
        const float bb = batt[col - 256];
#pragma unroll
        for (int j = 0; j < 4; ++j) awb[row0 + j][col - 256] = acc[i][j] + bb;
      }
    }
  }
  __syncthreads();

  if (t < 128) {  // softmax over 16 per (q, m): q = t>>3, m = t&7
    const int q = t >> 3, m = t & 7;
    float v[16]; float mx = -1e30f;
#pragma unroll
    for (int s = 0; s < 16; ++s) { v[s] = awb[q][m * 16 + s]; mx = fmaxf(mx, v[s]); }
    float sum = 0.f;
#pragma unroll
    for (int s = 0; s < 16; ++s) { v[s] = __expf(v[s] - mx); sum += v[s]; }
    const float inv = 1.f / sum;
#pragma unroll
    for (int s = 0; s < 16; ++s) awb[q][m * 16 + s] = v[s] * inv;
  }
  __syncthreads();

  // ---- sampling: wave-private, zero barriers ----
  const int qo  = lane >> 5;          // query parity within pair
  const int sh  = (lane >> 4) & 1;    // head within wave
  const int ss  = lane & 15;          // sample
  const int slv = ss >> 2;            // level (fixed per lane)
  const int WlS = 128 >> slv;
  const int stS = c_start[slv];
  const int st_eq = (2 * wave + sh) * 16 + ss;  // offb/awb column
  // gather mapping (R10 layout)
  const int hg = lane >> 5;
  const int m_g = 2 * wave + hg;
  const int g = lane & 31;
  const int sp = g >> 4, rsel = (g >> 3) & 1, csel = (g >> 2) & 1;
  const int wsel = (g >> 2) & 3, doct = g & 3;
  const char* vbyte = (const char*)vproj + (size_t)(n * M_ + m_g) * LEN_ * DH_ * 2;

  const float2* refp2 = (const float2*)refp;
  float2 rp[8];
#pragma unroll
  for (int e = 0; e < 8; ++e)
    rp[e] = refp2[(size_t)(qg0 + 2 * e + qo) * 4 + slv];

  for (int e = 0; e < 8; ++e) {
    {  // setup 2 queries (wave-private; in-order LDS, no barrier)
      const int q = 2 * e + qo;
      const float gx = rp[e].x * (float)WlS + bf2f(offb[q][2 * st_eq])     - 0.5f;
      const float gy = rp[e].y * (float)WlS + bf2f(offb[q][2 * st_eq + 1]) - 0.5f;
      const float fx0 = floorf(gx), fy0 = floorf(gy);
      const int x0 = (int)fx0, y0 = (int)fy0;
      const float wx1 = gx - fx0, wy1 = gy - fy0;
      const float wx0 = 1.f - wx1, wy0 = 1.f - wy1;
      const float a = awb[q][st_eq];
      const bool vx0 = (x0 >= 0) && (x0 < WlS);
      const bool vx1 = (x0 + 1 >= 0) && (x0 + 1 < WlS);
      const bool vy0 = (y0 >= 0) && (y0 < WlS);
      const bool vy1 = (y0 + 1 >= 0) && (y0 + 1 < WlS);
      sidx[wave][qo][sh][ss] = (short)(stS + y0 * WlS + x0);
      swls[wave][qo][sh][ss][0] = (vy0 && vx0) ? wy0 * wx0 * a : 0.f;
      swls[wave][qo][sh][ss][1] = (vy0 && vx1) ? wy0 * wx1 * a : 0.f;
      swls[wave][qo][sh][ss][2] = (vy1 && vx0) ? wy1 * wx0 * a : 0.f;
      swls[wave][qo][sh][ss][3] = (vy1 && vx1) ? wy1 * wx1 * a : 0.f;
    }

#pragma unroll
    for (int qo2 = 0; qo2 < 2; ++qo2) {
      const int qp = 2 * e + qo2;
      uint4 u0, u1, u2, u3, u4, u5, u6, u7;
      float w0, w1, w2, w3, w4, w5, w6, w7;
#define GLD(i, WLC)                                                        \
      {                                                                    \
        const int s_ = 2 * (i) + sp;                                       \
        const int ix_ = (int)sidx[wave][qo2][hg][s_];                      \
        w##i = swls[wave][qo2][hg][s_][wsel];                              \
        int ofs_ = (ix_ + rsel * (WLC) + csel) * 64 + doct * 16;           \
        ofs_ = (ofs_ > 0) ? ofs_ : 0;                                      \
        u##i = *(const uint4*)(vbyte + ofs_);                              \
      }
      GLD(0, 128) GLD(1, 128) GLD(2, 64) GLD(3, 64)
      GLD(4, 32)  GLD(5, 32)  GLD(6, 16) GLD(7, 16)
#undef GLD

      __builtin_amdgcn_s_setprio(1);
      float acc0 = 0.f, acc1 = 0.f, acc2 = 0.f, acc3 = 0.f;
      float acc4 = 0.f, acc5 = 0.f, acc6 = 0.f, acc7 = 0.f;
#define FMA8(i)                                                            \
      acc0 += bflo(u##i.x) * w##i; acc1 += bfhi(u##i.x) * w##i;            \
      acc2 += bflo(u##i.y) * w##i; acc3 += bfhi(u##i.y) * w##i;            \
      acc4 += bflo(u##i.z) * w##i; acc5 += bfhi(u##i.z) * w##i;            \
      acc6 += bflo(u##i.w) * w##i; acc7 += bfhi(u##i.w) * w##i;
      FMA8(0) FMA8(1) FMA8(2) FMA8(3) FMA8(4) FMA8(5) FMA8(6) FMA8(7)
#undef FMA8

      acc0 += __shfl_xor(acc0, 4);  acc1 += __shfl_xor(acc1, 4);
      acc2 += __shfl_xor(acc2, 4);  acc3 += __shfl_xor(acc3, 4);
      acc4 += __shfl_xor(acc4, 4);  acc5 += __shfl_xor(acc5, 4);
      acc6 += __shfl_xor(acc6, 4);  acc7 += __shfl_xor(acc7, 4);
      acc0 += __shfl_xor(acc0, 8);  acc1 += __shfl_xor(acc1, 8);
      acc2 += __shfl_xor(acc2, 8);  acc3 += __shfl_xor(acc3, 8);
      acc4 += __shfl_xor(acc4, 8);  acc5 += __shfl_xor(acc5, 8);
      acc6 += __shfl_xor(acc6, 8);  acc7 += __shfl_xor(acc7, 8);
      acc0 += __shfl_xor(acc0, 16); acc1 += __shfl_xor(acc1, 16);
      acc2 += __shfl_xor(acc2, 16); acc3 += __shfl_xor(acc3, 16);
      acc4 += __shfl_xor(acc4, 16); acc5 += __shfl_xor(acc5, 16);
      acc6 += __shfl_xor(acc6, 16); acc7 += __shfl_xor(acc7, 16);

      if (g < 4) {
        uint4 st4;
        st4.x = (unsigned int)f2bf(acc0) | ((unsigned int)f2bf(acc1) << 16);
        st4.y = (unsigned int)f2bf(acc2) | ((unsigned int)f2bf(acc3) << 16);
        st4.z = (unsigned int)f2bf(acc4) | ((unsigned int)f2bf(acc5) << 16);
        st4.w = (unsigned int)f2bf(acc6) | ((unsigned int)f2bf(acc7) << 16);
        *(uint4*)&qs[qp][m_g * 32 + doct * 8] = st4;
      }
      __builtin_amdgcn_s_setprio(0);
    }
  }
  __syncthreads();

  {  // out GEMM: mid [16x256] @ Wout [256x256], wave covers 4 col-tiles
    floatx4 acc[4] = {};
    for (int kk = 0; kk < 8; ++kk) {
      const int k0 = kk * 32;
      short8 af = *(const short8*)&qs[arow][k0 + kg];
#pragma unroll
      for (int i = 0; i < 4; ++i) {
        const int col = wave * 64 + i * 16 + (lane & 15);
        short8 bf = *(const short8*)(wt + 98304 + col * 256 + k0 + kg);
        acc[i] = __builtin_amdgcn_mfma_f32_16x16x32_bf16(af, bf, acc[i], 0, 0, 0);
      }
    }
#pragma unroll
    for (int i = 0; i < 4; ++i) {
      const int col = wave * 64 + i * 16 + (lane & 15);
      const float bb = bout[col];
#pragma unroll
      for (int j = 0; j < 4; ++j)
        out[(size_t)(qg0 + row0 + j) * D_ + col] = acc[i][j] + bb;
    }
  }
}

extern "C" void kernel_launch(void* const* d_in, const int* in_sizes, int n_in,
                              void* d_out, int out_size, void* d_ws, size_t ws_size,
                              hipStream_t stream) {
  const float* query = (const float*)d_in[0];
  const float* refp  = (const float*)d_in[1];
  const float* value = (const float*)d_in[2];
  const float* Wv    = (const float*)d_in[4];
  const float* bv    = (const float*)d_in[5];
  const float* Woff  = (const float*)d_in[6];
  const float* boff  = (const float*)d_in[7];
  const float* Watt  = (const float*)d_in[8];
  const float* batt  = (const float*)d_in[9];
  const float* Wout  = (const float*)d_in[10];
  const float* bout  = (const float*)d_in[11];
  float* out = (float*)d_out;

  unsigned short* vproj = (unsigned short*)d_ws;
  unsigned short* wt    = (unsigned short*)((char*)d_ws + WT_BYTE_OFF);
  const unsigned short* Wvt = wt + 163840;

  dim3 blk(256);
  hipLaunchKernelGGL(prep_kernel, dim3(896), blk, 0, stream, Woff, Watt, Wout, Wv, wt);
  hipLaunchKernelGGL(vproj_kernel, dim3((N_ * LEN_) / 64), blk, 0, stream, value, Wvt, bv, vproj);
  hipLaunchKernelGGL(msda_kernel, dim3((N_ * LQ_) / BQ), blk, 0, stream,
                     query, refp, wt, boff, batt, bout, vproj, out);
}